// Round 8
// baseline (244.446 us; speedup 1.0000x reference)
//
#include <hip/hip_runtime.h>

#define Bn   2
#define Cn   64
#define Dd   8
#define Hd   128
#define Wd   128
#define HW   16384
#define DHW  131072     // 2^17
#define NPOS 262144     // 2^18
#define NELEM 16777216

typedef __attribute__((ext_vector_type(8))) short short8;
typedef __attribute__((ext_vector_type(4))) float floatx4;

// Truncation split: hi = upper16(f), lo = trunc16(f - hi). Pair error ~2^-17 rel.
__device__ __forceinline__ void split2(float f, short& hi, short& lo) {
    union { float f; unsigned u; } a; a.f = f;
    unsigned hu = a.u & 0xFFFF0000u;
    hi = (short)(hu >> 16);
    union { unsigned u; float f; } hb; hb.u = hu;
    union { float f; unsigned u; } lb; lb.f = f - hb.f;
    lo = (short)(lb.u >> 16);
}

// ---------------------------------------------------------------------------
// k_headm: [h | Vp] = Wh[80x64] @ x, split-bf16 MFMA (fp32-class).
// X staged fp32 natural-layout via float4 loads; split at frag-read.
// V^T@head_w rows computed inline (drops k_prep). Two-phase LDS epilogue.
// ---------------------------------------------------------------------------
__global__ __launch_bounds__(256) void k_headm(const float* __restrict__ x,
                                               const float* __restrict__ head_w,
                                               const float* __restrict__ V_w,
                                               float* __restrict__ h,
                                               float* __restrict__ Vp)
{
    __shared__ __align__(16) char smem[54016];
    float* Xn  = (float*)smem;                   // [64][128] fp32, 32768 B
    short* BhA = (short*)(smem + 32768);         // 10 frag-blocks, 10240 B
    short* BlA = (short*)(smem + 43008);         // 10240 B
    float* vwf = (float*)(smem + 53248);         // [3][64] V^T @ head_w
    float* Cb  = (float*)smem;                   // epilogue overlay [80][72]

    int t  = threadIdx.x;
    int p0 = blockIdx.x * 128;
    int b  = p0 >> 17;
    int s0 = p0 & (DHW - 1);
    const float* xb = x + (size_t)b * Cn * DHW + s0;

    // X stage: float4 global loads (16B/lane), natural [ch][128] layout
    floatx4 xr[8];
#pragma unroll
    for (int ps = 0; ps < 8; ++ps) {
        int u = ps * 256 + t;
        int ch = u >> 5, pg = u & 31;
        xr[ps] = *(const floatx4*)(xb + (size_t)ch * DHW + pg * 4);
    }
    if (t < 192) {                               // vw[r][i] = sum_c V[c][r]*W[c][i]
        int r = t >> 6, i = t & 63;
        float s = 0.f;
        for (int cc = 0; cc < 64; ++cc)
            s += V_w[cc * 3 + r] * head_w[cc * 64 + i];
        vwf[t] = s;
    }
#pragma unroll
    for (int ps = 0; ps < 8; ++ps) {
        int u = ps * 256 + t;
        int ch = u >> 5, pg = u & 31;
        *(floatx4*)&Xn[ch * 128 + pg * 4] = xr[ps];
    }
    __syncthreads();

    // B frags from global weights / LDS vw: 640 units (o 0..79, oc 0..7)
#pragma unroll
    for (int ps = 0; ps < 3; ++ps) {
        int unit = ps * 256 + t;
        if (unit < 640) {
            int o  = unit % 80;
            int oc = unit / 80;
            short8 vh, vl;
            if (o < 64) {
                const float* wr = head_w + o * 64 + oc * 8;
#pragma unroll
                for (int j = 0; j < 8; ++j) { short hi, lo; split2(wr[j], hi, lo); vh[j] = hi; vl[j] = lo; }
            } else if (o < 67) {
                const float* wr = vwf + (o - 64) * 64 + oc * 8;
#pragma unroll
                for (int j = 0; j < 8; ++j) { short hi, lo; split2(wr[j], hi, lo); vh[j] = hi; vl[j] = lo; }
            } else {
#pragma unroll
                for (int j = 0; j < 8; ++j) { vh[j] = 0; vl[j] = 0; }
            }
            int blk  = ((o >> 4) << 1) | (oc >> 2);
            int slot = ((oc & 3) << 4) | (o & 15);
            *(short8*)&BhA[(blk * 64 + slot) * 8] = vh;
            *(short8*)&BlA[(blk * 64 + slot) * 8] = vl;
        }
    }
    __syncthreads();

    int lane = t & 63, w = t >> 6;
    int quad = lane >> 4, sidx = lane & 15;
    floatx4 acc[2][5];
#pragma unroll
    for (int mt = 0; mt < 2; ++mt)
#pragma unroll
        for (int nt = 0; nt < 5; ++nt) acc[mt][nt] = (floatx4)0.f;

#pragma unroll
    for (int ks = 0; ks < 2; ++ks) {
        short8 ah[2], al[2];
#pragma unroll
        for (int mt = 0; mt < 2; ++mt) {
            int pbase = w * 32 + mt * 16 + sidx;
            int kbase = ks * 32 + quad * 8;
#pragma unroll
            for (int j = 0; j < 8; ++j) {
                short hi, lo;
                split2(Xn[(kbase + j) * 128 + pbase], hi, lo);
                ah[mt][j] = hi; al[mt][j] = lo;
            }
        }
#pragma unroll
        for (int nt = 0; nt < 5; ++nt) {
            short8 bh = *(const short8*)&BhA[((nt * 2 + ks) * 64 + lane) * 8];
            short8 bl = *(const short8*)&BlA[((nt * 2 + ks) * 64 + lane) * 8];
#pragma unroll
            for (int mt = 0; mt < 2; ++mt) {
                acc[mt][nt] = __builtin_amdgcn_mfma_f32_16x16x32_bf16(al[mt], bh, acc[mt][nt], 0, 0, 0);
                acc[mt][nt] = __builtin_amdgcn_mfma_f32_16x16x32_bf16(ah[mt], bl, acc[mt][nt], 0, 0, 0);
                acc[mt][nt] = __builtin_amdgcn_mfma_f32_16x16x32_bf16(ah[mt], bh, acc[mt][nt], 0, 0, 0);
            }
        }
    }

    // Two-phase epilogue through Cb (overlays Xn; frag reads complete)
#pragma unroll
    for (int mt = 0; mt < 2; ++mt) {
        __syncthreads();
#pragma unroll
        for (int nt = 0; nt < 5; ++nt)
            *(floatx4*)&Cb[(nt * 16 + sidx) * 72 + w * 16 + quad * 4] = acc[mt][nt];
        __syncthreads();
#pragma unroll
        for (int ps = 0; ps < 5; ++ps) {
            int u = ps * 256 + t;
            int o = u >> 4, g = u & 15;
            floatx4 vv = *(const floatx4*)&Cb[o * 72 + g * 4];
            int pos = (g >> 2) * 32 + mt * 16 + (g & 3) * 4;
            if (o < 64)
                *(floatx4*)&h[((size_t)(b * Cn + o)) * DHW + s0 + pos] = vv;
            else if (o < 67)
                *(floatx4*)&Vp[((size_t)(b * 3 + (o - 64))) * DHW + s0 + pos] = vv;
        }
    }
}

// ---------------------------------------------------------------------------
// k_uv: fp32 depthwise 3x3x3 (replicate pad) -> l2norm over r -> dot Vp.
// x-blocked 4 outputs/thread: padded LDS rows (p=x+1, width 132) make each
// (slice,row) window two aligned ds_read_b128 (24 LDS reads/thread vs 72).
// Padded col range is p=0..129: p=0 <- x=0, p=129 <- x=127 (off-by-one fixed).
// ---------------------------------------------------------------------------
#define CONTRIB(oi, dk)                                                     \
    {                                                                       \
        _Pragma("unroll")                                                   \
        for (int kh = 0; kh < 3; ++kh) {                                    \
            _Pragma("unroll")                                               \
            for (int kw = 0; kw < 3; ++kw) {                                \
                const int kk = (((dk) * 3 + kh) * 3 + kw) * 3;              \
                float w0 = U_w[kk + 0], w1 = U_w[kk + 1], w2 = U_w[kk + 2]; \
                _Pragma("unroll")                                           \
                for (int xi = 0; xi < 4; ++xi) {                            \
                    float hv = v[kh][xi + kw];                              \
                    a[oi][0][xi] += hv * w0;                                \
                    a[oi][1][xi] += hv * w1;                                \
                    a[oi][2][xi] += hv * w2;                                \
                }                                                           \
            }                                                               \
        }                                                                   \
    }

__global__ __launch_bounds__(256) void k_uv(const float* __restrict__ h,
                                            const float* __restrict__ Vp,
                                            const float* __restrict__ U_w,
                                            float* __restrict__ UV)
{
    __shared__ float tile[Dd][4][132];   // p = x+1; 16896 B

    int blk = blockIdx.x;
    int yt  = blk & 63;
    int bc  = blk >> 6;                  // b*64 + c
    int b   = bc >> 6;
    int y0  = yt * 2;
    int t   = threadIdx.x;

    const float* hb = h + (size_t)bc * DHW;
#pragma unroll
    for (int rep = 0; rep < 4; ++rep) {  // interior: 1024 float4 units
        int u  = rep * 256 + t;
        int d  = u >> 7;
        int rm = u & 127;
        int yr = rm >> 5;
        int pg = rm & 31;
        int zy = y0 - 1 + yr;
        zy = zy < 0 ? 0 : (zy > Hd - 1 ? Hd - 1 : zy);
        floatx4 v4 = *(const floatx4*)(hb + d * HW + zy * Wd + pg * 4);
#pragma unroll
        for (int j = 0; j < 4; ++j) tile[d][yr][1 + pg * 4 + j] = v4[j];
    }
    if (t < 64) {                        // replicate edge columns p=0 (x=0), p=129 (x=127)
        int d = t >> 3, rm = t & 7;
        int yr = rm >> 1, side = rm & 1;
        int zy = y0 - 1 + yr;
        zy = zy < 0 ? 0 : (zy > Hd - 1 ? Hd - 1 : zy);
        tile[d][yr][side ? 129 : 0] = hb[d * HW + zy * Wd + (side ? 127 : 0)];
    }
    __syncthreads();

    int xg = t & 31, x4 = xg * 4;
    int yr_out = (t >> 5) & 1;
    int dg = t >> 6;
    int d0 = dg * 2;
    int y  = y0 + yr_out;

    float a[2][3][4];
#pragma unroll
    for (int oi = 0; oi < 2; ++oi)
#pragma unroll
        for (int r = 0; r < 3; ++r)
#pragma unroll
            for (int xi = 0; xi < 4; ++xi) a[oi][r][xi] = 0.f;

#pragma unroll
    for (int si = 0; si < 4; ++si) {     // raw slice zs = d0-1+si; (oi,dk): oi+dk == si
        int zs  = d0 - 1 + si;
        int zsc = zs < 0 ? 0 : (zs > 7 ? 7 : zs);
        float v[3][8];
#pragma unroll
        for (int kh = 0; kh < 3; ++kh) {
            floatx4 lo4 = *(const floatx4*)&tile[zsc][yr_out + kh][x4];
            floatx4 hi4 = *(const floatx4*)&tile[zsc][yr_out + kh][x4 + 4];
#pragma unroll
            for (int j = 0; j < 4; ++j) { v[kh][j] = lo4[j]; v[kh][4 + j] = hi4[j]; }
        }
        if (si == 0) CONTRIB(0, 0);
        if (si == 1) { CONTRIB(0, 1); CONTRIB(1, 0); }
        if (si == 2) { CONTRIB(0, 2); CONTRIB(1, 1); }
        if (si == 3) CONTRIB(1, 2);
    }

    size_t base_uv = (size_t)bc * DHW + y * Wd + x4;
    size_t base_vp = ((size_t)b * 3) * DHW + y * Wd + x4;
#pragma unroll
    for (int oi = 0; oi < 2; ++oi) {
        int d = d0 + oi;
        floatx4 vp0 = *(const floatx4*)&Vp[base_vp + (size_t)0 * DHW + d * HW];
        floatx4 vp1 = *(const floatx4*)&Vp[base_vp + (size_t)1 * DHW + d * HW];
        floatx4 vp2 = *(const floatx4*)&Vp[base_vp + (size_t)2 * DHW + d * HW];
        floatx4 uv;
#pragma unroll
        for (int xi = 0; xi < 4; ++xi) {
            float a0 = a[oi][0][xi], a1 = a[oi][1][xi], a2 = a[oi][2][xi];
            float nrm = sqrtf(a0 * a0 + a1 * a1 + a2 * a2);
            float inv = 1.f / (1e-6f + nrm);
            uv[xi] = (a0 * vp0[xi] + a1 * vp1[xi] + a2 * vp2[xi]) * inv;
        }
        *(floatx4*)&UV[base_uv + d * HW] = uv;
    }
}
#undef CONTRIB

// ---------------------------------------------------------------------------
// k_tailm: out = Wt[64x64] @ UV, same structure as k_headm (no vw rows).
// ---------------------------------------------------------------------------
__global__ __launch_bounds__(256) void k_tailm(const float* __restrict__ UV,
                                               const float* __restrict__ tail_w,
                                               float* __restrict__ out)
{
    __shared__ __align__(16) char smem[49152];
    float* Xn  = (float*)smem;                   // [64][128] fp32, 32768 B
    short* BhA = (short*)(smem + 32768);         // 8 frag-blocks, 8192 B
    short* BlA = (short*)(smem + 40960);         // 8192 B
    float* Cb  = (float*)smem;                   // epilogue overlay [64][72]

    int t  = threadIdx.x;
    int p0 = blockIdx.x * 128;
    int b  = p0 >> 17;
    int s0 = p0 & (DHW - 1);
    const float* ub = UV + (size_t)b * Cn * DHW + s0;

    floatx4 xr[8];
#pragma unroll
    for (int ps = 0; ps < 8; ++ps) {
        int u = ps * 256 + t;
        int ch = u >> 5, pg = u & 31;
        xr[ps] = *(const floatx4*)(ub + (size_t)ch * DHW + pg * 4);
    }
#pragma unroll
    for (int ps = 0; ps < 8; ++ps) {
        int u = ps * 256 + t;
        int ch = u >> 5, pg = u & 31;
        *(floatx4*)&Xn[ch * 128 + pg * 4] = xr[ps];
    }
    // B frags: 512 units (o 0..63, oc 0..7)
#pragma unroll
    for (int ps = 0; ps < 2; ++ps) {
        int unit = ps * 256 + t;
        int o  = unit & 63;
        int oc = unit >> 6;
        const float* wr = tail_w + o * 64 + oc * 8;
        short8 vh, vl;
#pragma unroll
        for (int j = 0; j < 8; ++j) { short hi, lo; split2(wr[j], hi, lo); vh[j] = hi; vl[j] = lo; }
        int blk  = ((o >> 4) << 1) | (oc >> 2);
        int slot = ((oc & 3) << 4) | (o & 15);
        *(short8*)&BhA[(blk * 64 + slot) * 8] = vh;
        *(short8*)&BlA[(blk * 64 + slot) * 8] = vl;
    }
    __syncthreads();

    int lane = t & 63, w = t >> 6;
    int quad = lane >> 4, sidx = lane & 15;
    floatx4 acc[2][4];
#pragma unroll
    for (int mt = 0; mt < 2; ++mt)
#pragma unroll
        for (int nt = 0; nt < 4; ++nt) acc[mt][nt] = (floatx4)0.f;

#pragma unroll
    for (int ks = 0; ks < 2; ++ks) {
        short8 ah[2], al[2];
#pragma unroll
        for (int mt = 0; mt < 2; ++mt) {
            int pbase = w * 32 + mt * 16 + sidx;
            int kbase = ks * 32 + quad * 8;
#pragma unroll
            for (int j = 0; j < 8; ++j) {
                short hi, lo;
                split2(Xn[(kbase + j) * 128 + pbase], hi, lo);
                ah[mt][j] = hi; al[mt][j] = lo;
            }
        }
#pragma unroll
        for (int nt = 0; nt < 4; ++nt) {
            short8 bh = *(const short8*)&BhA[((nt * 2 + ks) * 64 + lane) * 8];
            short8 bl = *(const short8*)&BlA[((nt * 2 + ks) * 64 + lane) * 8];
#pragma unroll
            for (int mt = 0; mt < 2; ++mt) {
                acc[mt][nt] = __builtin_amdgcn_mfma_f32_16x16x32_bf16(al[mt], bh, acc[mt][nt], 0, 0, 0);
                acc[mt][nt] = __builtin_amdgcn_mfma_f32_16x16x32_bf16(ah[mt], bl, acc[mt][nt], 0, 0, 0);
                acc[mt][nt] = __builtin_amdgcn_mfma_f32_16x16x32_bf16(ah[mt], bh, acc[mt][nt], 0, 0, 0);
            }
        }
    }

#pragma unroll
    for (int mt = 0; mt < 2; ++mt) {
        __syncthreads();
#pragma unroll
        for (int nt = 0; nt < 4; ++nt)
            *(floatx4*)&Cb[(nt * 16 + sidx) * 72 + w * 16 + quad * 4] = acc[mt][nt];
        __syncthreads();
#pragma unroll
        for (int ps = 0; ps < 4; ++ps) {
            int u = ps * 256 + t;
            int o = u >> 4, g = u & 15;
            floatx4 vv = *(const floatx4*)&Cb[o * 72 + g * 4];
            int pos = (g >> 2) * 32 + mt * 16 + (g & 3) * 4;
            *(floatx4*)&out[((size_t)(b * Cn + o)) * DHW + s0 + pos] = vv;
        }
    }
}

extern "C" void kernel_launch(void* const* d_in, const int* in_sizes, int n_in,
                              void* d_out, int out_size, void* d_ws, size_t ws_size,
                              hipStream_t stream)
{
    const float* x      = (const float*)d_in[0];
    const float* head_w = (const float*)d_in[1];
    const float* tail_w = (const float*)d_in[2];
    const float* U_w    = (const float*)d_in[3];
    const float* V_w    = (const float*)d_in[4];
    float* out = (float*)d_out;

    // ws: h fp32 (64MB) | Vp fp32 (3MB) | UV fp32 (64MB)
    float* h   = (float*)d_ws;
    float* Vp  = h + (size_t)NELEM;
    float* UVf = Vp + (size_t)Bn * 3 * DHW;

    k_headm<<<NPOS / 128, 256, 0, stream>>>(x, head_w, V_w, h, Vp);
    k_uv<<<Bn * Cn * (Hd / 2), 256, 0, stream>>>(h, Vp, U_w, UVf);
    k_tailm<<<NPOS / 128, 256, 0, stream>>>(UVf, tail_w, out);
}